// Round 4
// baseline (432.734 us; speedup 1.0000x reference)
//
#include <hip/hip_runtime.h>

// Linear state-space scan:  x_{k+1} = A x_k + B u_k ; outputs X_k (pre-step
// state) and y_k = C x_k + D u_k (normalized in, denormalized out).
// N=16384 steps, R=256 columns, NX=8, NU=NY=2.
//
// SINGLE-KERNEL flag-synced parallel scan.
//   Round-3 lesson (measured): per-THREAD release fetch_adds (131k lane-
//   atomics on 1-2 cachelines) serialize at the L2 atomic unit ~4clk each
//   ~= 220us of idle. Publish must be BLOCK-granular:
//     stores -> __threadfence() -> __syncthreads() -> thread0 release add.
//   Consumer: thread0 relaxed spin -> acquire load -> __syncthreads fan-out.
//   512 blocks x 256 thr, 2 blocks/CU -> ALL co-resident (spin-safe).
//   phase A : normalize u -> 64KB LDS (kept for replay), zero-state d32.
//   combiner (c&7==7): cnt[m]==7 -> Horner_{A32} -> d256[m]; dcnt==64 ->
//             parallel lookback s256[m] = Horner_{A256}(d256[0..m-1]) from
//             x0 (same op sequence as the verified serial phase2); fs[m]=1.
//   all     : fs[m] -> advance p=c&7 fine chunks via d32, replay 32 steps
//             from LDS u, nt-store X and denorm Y.

#define NSTEPS 16384
#define NUI 2
#define RB 256
#define NXS 8
#define NYO 2
#define LF 32
#define NC1 (NSTEPS / LF)   // 512 fine chunks (32 steps each)
#define NSUP 8              // fine chunks per super-chunk
#define NC2B (NC1 / NSUP)   // 64 super-chunks of 256 steps
#define CNT_TGT 7u          // 7 producer blocks, 1 add each
#define DCNT_TGT ((unsigned)NC2B)
#define FS_TGT 1u

__device__ __forceinline__ void publish(unsigned int* f) {
    __threadfence();          // drain this thread's stores, wbl2 (per-wave)
    __syncthreads();          // all waves' fences complete before t0's add
    if (threadIdx.x == 0)
        __hip_atomic_fetch_add(f, 1u, __ATOMIC_RELEASE,
                               __HIP_MEMORY_SCOPE_AGENT);
}

__device__ __forceinline__ void waitflag(unsigned int* f, unsigned int tgt) {
    if (threadIdx.x == 0) {
        while (__hip_atomic_load(f, __ATOMIC_RELAXED, __HIP_MEMORY_SCOPE_AGENT) < tgt)
            __builtin_amdgcn_s_sleep(2);
        (void)__hip_atomic_load(f, __ATOMIC_ACQUIRE, __HIP_MEMORY_SCOPE_AGENT);
    }
    __syncthreads();   // fan-out: block-uniform call sites only
}

__global__ __launch_bounds__(RB, 2) void fused_k(
    const float* __restrict__ u, const float* __restrict__ x0,
    const float* __restrict__ A, const float* __restrict__ Bu,
    const float* __restrict__ Cy, const float* __restrict__ Dyu,
    const float* __restrict__ um, const float* __restrict__ us,
    const float* __restrict__ ym, const float* __restrict__ ys,
    float* __restrict__ Y, float* __restrict__ X,
    float* __restrict__ d32, float* __restrict__ d256,
    float* __restrict__ s256, unsigned int* __restrict__ flags) {
    __shared__ float uL[LF][NUI][RB];   // 64 KB normalized u (this chunk)
    __shared__ float Ms[64];
    __shared__ float A32s[64];
    __shared__ float A256s[64];

    const int c = blockIdx.x;   // 0..511
    const int t = threadIdx.x;
    const int r = t;            // column
    const int m = c >> 3;       // super-chunk
    const int p = c & 7;        // position in super-chunk (block-uniform)
    unsigned int* cnt  = flags;             // [NC2B]
    unsigned int* dcnt = flags + NC2B;      // [1]
    unsigned int* fs   = flags + NC2B + 1;  // [NC2B]

    // ---- phase A: normalize u -> LDS, zero-state 32-step response ----
    float a[NXS][NXS];
    #pragma unroll
    for (int i = 0; i < NXS; ++i)
        #pragma unroll
        for (int j = 0; j < NXS; ++j) a[i][j] = A[i * NXS + j];
    float b0[NXS], b1[NXS];
    #pragma unroll
    for (int i = 0; i < NXS; ++i) { b0[i] = Bu[i * NUI]; b1[i] = Bu[i * NUI + 1]; }
    const float um0 = um[0], um1 = um[1];
    const float is0 = 1.0f / us[0], is1 = 1.0f / us[1];
    float tv[NXS];
    #pragma unroll
    for (int i = 0; i < NXS; ++i) tv[i] = 0.f;
    {
        const float* up = u + (size_t)c * LF * NUI * RB + r;
        #pragma unroll 4
        for (int j = 0; j < LF; ++j) {
            const float u0 = (up[0]  - um0) * is0;
            const float u1 = (up[RB] - um1) * is1;
            up += NUI * RB;
            uL[j][0][r] = u0;
            uL[j][1][r] = u1;
            float nt[NXS];
            #pragma unroll
            for (int i = 0; i < NXS; ++i) {
                float acc = fmaf(b0[i], u0, b1[i] * u1);
                #pragma unroll
                for (int k = 0; k < NXS; ++k) acc = fmaf(a[i][k], tv[k], acc);
                nt[i] = acc;
            }
            #pragma unroll
            for (int i = 0; i < NXS; ++i) tv[i] = nt[i];
        }
    }
    if (p != 7) {   // combiner's own slice is never read by others
        float* dp = d32 + (size_t)c * NXS * RB + r;
        #pragma unroll
        for (int i = 0; i < NXS; ++i) dp[i * RB] = tv[i];
        publish(&cnt[m]);          // block-granular: 1 atomic per block
    }

    // ---- A powers ladder (overlaps other blocks' phase A) ----
    if (t < 64) Ms[t] = A[t];
    __syncthreads();
    {
        const int pi = t >> 3, pj = t & 7;
        #pragma unroll
        for (int it = 0; it < 8; ++it) {   // A^2 .. A^256
            float acc = 0.f;
            if (t < 64) {
                #pragma unroll
                for (int k = 0; k < 8; ++k) acc += Ms[pi * 8 + k] * Ms[k * 8 + pj];
            }
            __syncthreads();
            if (t < 64) {
                Ms[t] = acc;
                if (it == 4) A32s[t] = acc;   // A^32
            }
            __syncthreads();
        }
        if (t < 64) A256s[t] = Ms[t];          // A^256
        __syncthreads();
    }

    float sb[NXS];   // start state of super-chunk m for this column

    if (p == 7) {
        // ---------------- combiner ----------------
        float xv[NXS];
        #pragma unroll
        for (int i = 0; i < NXS; ++i) xv[i] = x0[i * RB + r];

        waitflag(&cnt[m], CNT_TGT);
        {
            float a32[NXS][NXS];
            #pragma unroll
            for (int i = 0; i < NXS; ++i)
                #pragma unroll
                for (int j = 0; j < NXS; ++j) a32[i][j] = A32s[i * 8 + j];
            float xq[NSUP - 1][NXS];
            #pragma unroll
            for (int q = 0; q < NSUP - 1; ++q) {
                const float* dq = d32 + (size_t)(NSUP * m + q) * NXS * RB + r;
                #pragma unroll
                for (int i = 0; i < NXS; ++i) xq[q][i] = dq[i * RB];
            }
            float s[NXS];
            #pragma unroll
            for (int i = 0; i < NXS; ++i) s[i] = xq[0][i];
            #pragma unroll
            for (int q = 1; q < NSUP - 1; ++q) {
                float nt[NXS];
                #pragma unroll
                for (int i = 0; i < NXS; ++i) {
                    float acc = xq[q][i];
                    #pragma unroll
                    for (int k = 0; k < NXS; ++k) acc = fmaf(a32[i][k], s[k], acc);
                    nt[i] = acc;
                }
                #pragma unroll
                for (int i = 0; i < NXS; ++i) s[i] = nt[i];
            }
            {   // last term = own tv (in registers)
                float nt[NXS];
                #pragma unroll
                for (int i = 0; i < NXS; ++i) {
                    float acc = tv[i];
                    #pragma unroll
                    for (int k = 0; k < NXS; ++k) acc = fmaf(a32[i][k], s[k], acc);
                    nt[i] = acc;
                }
                #pragma unroll
                for (int i = 0; i < NXS; ++i) s[i] = nt[i];
            }
            float* o = d256 + (size_t)m * NXS * RB + r;
            #pragma unroll
            for (int i = 0; i < NXS; ++i) o[i * RB] = s[i];
        }
        publish(dcnt);

        // lookback: sb = Horner_{A256}(d256[0..m-1]) from x0
        #pragma unroll
        for (int i = 0; i < NXS; ++i) sb[i] = xv[i];
        if (m > 0) {
            waitflag(dcnt, DCNT_TGT);
            float a256[NXS][NXS];
            #pragma unroll
            for (int i = 0; i < NXS; ++i)
                #pragma unroll
                for (int j = 0; j < NXS; ++j) a256[i][j] = A256s[i * 8 + j];
            for (int base = 0; base < m; base += 8) {   // <=8 tiles
                float T[8][NXS];
                #pragma unroll
                for (int k = 0; k < 8; ++k) {
                    if (base + k < m) {
                        const float* dq = d256 + (size_t)(base + k) * NXS * RB + r;
                        #pragma unroll
                        for (int i = 0; i < NXS; ++i) T[k][i] = dq[i * RB];
                    }
                }
                #pragma unroll
                for (int k = 0; k < 8; ++k) {
                    if (base + k < m) {
                        float nt[NXS];
                        #pragma unroll
                        for (int i = 0; i < NXS; ++i) {
                            float acc = T[k][i];
                            #pragma unroll
                            for (int kk = 0; kk < NXS; ++kk)
                                acc = fmaf(a256[i][kk], sb[kk], acc);
                            nt[i] = acc;
                        }
                        #pragma unroll
                        for (int i = 0; i < NXS; ++i) sb[i] = nt[i];
                    }
                }
            }
        }
        {
            float* sp = s256 + (size_t)m * NXS * RB + r;
            #pragma unroll
            for (int i = 0; i < NXS; ++i) sp[i * RB] = sb[i];
        }
        publish(&fs[m]);
    } else {
        // ---------------- consumer ----------------
        waitflag(&fs[m], FS_TGT);
        const float* sp = s256 + (size_t)m * NXS * RB + r;
        #pragma unroll
        for (int i = 0; i < NXS; ++i) sb[i] = sp[i * RB];
    }

    // ---- advance start by p fine chunks: sb = A32 sb + d32[8m+q] ----
    if (p) {
        float a32[NXS][NXS];
        #pragma unroll
        for (int i = 0; i < NXS; ++i)
            #pragma unroll
            for (int j = 0; j < NXS; ++j) a32[i][j] = A32s[i * 8 + j];
        float P[NSUP - 1][NXS];
        #pragma unroll
        for (int q = 0; q < NSUP - 1; ++q) {
            if (q < p) {
                const float* dq = d32 + (size_t)(NSUP * m + q) * NXS * RB + r;
                #pragma unroll
                for (int i = 0; i < NXS; ++i) P[q][i] = dq[i * RB];
            }
        }
        #pragma unroll
        for (int q = 0; q < NSUP - 1; ++q) {
            if (q < p) {
                float nt[NXS];
                #pragma unroll
                for (int i = 0; i < NXS; ++i) {
                    float acc = P[q][i];
                    #pragma unroll
                    for (int k = 0; k < NXS; ++k) acc = fmaf(a32[i][k], sb[k], acc);
                    nt[i] = acc;
                }
                #pragma unroll
                for (int i = 0; i < NXS; ++i) sb[i] = nt[i];
            }
        }
    }

    // ---- replay 32 steps from LDS u; nt-store X and denormalized Y ----
    float c0[NXS], c1[NXS];
    #pragma unroll
    for (int k = 0; k < NXS; ++k) { c0[k] = Cy[k]; c1[k] = Cy[NXS + k]; }
    const float d00 = Dyu[0], d01 = Dyu[1], d10 = Dyu[2], d11 = Dyu[3];
    const float ym0 = ym[0], ym1 = ym[1], ys0 = ys[0], ys1 = ys[1];
    float* Xp = X + (size_t)c * LF * NXS * RB + r;
    float* Yp = Y + (size_t)c * LF * NYO * RB + r;
    #pragma unroll 4
    for (int j = 0; j < LF; ++j) {
        const float u0 = uL[j][0][r];
        const float u1 = uL[j][1][r];
        #pragma unroll
        for (int i = 0; i < NXS; ++i)
            __builtin_nontemporal_store(sb[i], Xp + i * RB);
        Xp += NXS * RB;
        float y0 = fmaf(d00, u0, d01 * u1);
        float y1 = fmaf(d10, u0, d11 * u1);
        #pragma unroll
        for (int k = 0; k < NXS; ++k) {
            y0 = fmaf(c0[k], sb[k], y0);
            y1 = fmaf(c1[k], sb[k], y1);
        }
        __builtin_nontemporal_store(fmaf(y0, ys0, ym0), Yp);
        __builtin_nontemporal_store(fmaf(y1, ys1, ym1), Yp + RB);
        Yp += NYO * RB;
        float nt[NXS];
        #pragma unroll
        for (int i = 0; i < NXS; ++i) {
            float acc = fmaf(b0[i], u0, b1[i] * u1);
            #pragma unroll
            for (int k = 0; k < NXS; ++k) acc = fmaf(a[i][k], sb[k], acc);
            nt[i] = acc;
        }
        #pragma unroll
        for (int i = 0; i < NXS; ++i) sb[i] = nt[i];
    }
}

extern "C" void kernel_launch(void* const* d_in, const int* in_sizes, int n_in,
                              void* d_out, int out_size, void* d_ws, size_t ws_size,
                              hipStream_t stream) {
    const float* u   = (const float*)d_in[0];
    const float* x0  = (const float*)d_in[1];
    const float* A   = (const float*)d_in[2];
    const float* Bu  = (const float*)d_in[3];
    const float* Cy  = (const float*)d_in[4];
    const float* Dyu = (const float*)d_in[5];
    const float* um  = (const float*)d_in[6];
    const float* us  = (const float*)d_in[7];
    const float* ym  = (const float*)d_in[8];
    const float* ys  = (const float*)d_in[9];

    float* Y = (float*)d_out;                       // (N, NY, R)
    float* X = Y + (size_t)NSTEPS * NYO * RB;       // (N, NX, R)

    float* ws   = (float*)d_ws;
    float* d32  = ws;                               // NC1*NX*R  = 4 MB
    float* d256 = d32 + (size_t)NC1 * NXS * RB;     // NC2B*NX*R = 512 KB
    float* s256 = d256 + (size_t)NC2B * NXS * RB;   // NC2B*NX*R = 512 KB
    unsigned int* flags = (unsigned int*)(s256 + (size_t)NC2B * NXS * RB);

    // flags must be zero each run (ws may be poisoned between iterations)
    hipMemsetAsync(flags, 0, 1024, stream);
    fused_k<<<NC1, RB, 0, stream>>>(u, x0, A, Bu, Cy, Dyu, um, us, ym, ys,
                                    Y, X, d32, d256, s256, flags);
}

// Round 5
// 423.125 us; speedup vs baseline: 1.0227x; 1.0227x over previous
//
#include <hip/hip_runtime.h>

// Linear state-space scan:  x_{k+1} = A x_k + B u_k ; outputs X_k (pre-step
// state) and y_k = C x_k + D u_k (normalized in, denormalized out).
// N=16384 steps, R=256 columns, NX=8, NU=NY=2.
//
// SINGLE-KERNEL flag-synced parallel scan.
//   Round-3 lesson: per-thread release atomics (131k) -> ~190us idle.
//   Round-4 lesson: block-granular publish (576 atomics) -> SAME idle (~220us)
//     => publisher-side serialization refuted. Shared mechanism: 512 blocks
//     SPIN-POLLING flags packed into 4-5 cachelines; agent-scope atomic loads
//     are serviced at the fabric coherence point, same-line ops serialize ->
//     standing queue -> every poll AND every publish waits a full drain.
//     (Also explains cg grid.sync's ~110us/sync: one arrive-counter line.)
//   THIS ROUND (single variable): pad each flag to its own 256-B slot
//     (FPAD=64 uints) -> <=7 pollers per line; s_sleep(16) softer poll.
//   512 blocks x 256 thr, 2 blocks/CU -> ALL co-resident (spin-safe).
//   phase A : normalize u -> 64KB LDS (kept for replay), zero-state d32.
//   combiner (c&7==7): cnt[m]==7 -> Horner_{A32} -> d256[m]; dcnt==64 ->
//             parallel lookback s256[m] = Horner_{A256}(d256[0..m-1]) from
//             x0 (same op sequence as the verified serial phase2); fs[m]=1.
//   all     : fs[m] -> advance p=c&7 fine chunks via d32, replay 32 steps
//             from LDS u, nt-store X and denorm Y.

#define NSTEPS 16384
#define NUI 2
#define RB 256
#define NXS 8
#define NYO 2
#define LF 32
#define NC1 (NSTEPS / LF)   // 512 fine chunks (32 steps each)
#define NSUP 8              // fine chunks per super-chunk
#define NC2B (NC1 / NSUP)   // 64 super-chunks of 256 steps
#define CNT_TGT 7u          // 7 producer blocks, 1 add each
#define DCNT_TGT ((unsigned)NC2B)
#define FS_TGT 1u
#define FPAD 64             // uints per flag slot = 256 B (own cacheline)

__device__ __forceinline__ void publish(unsigned int* f) {
    __threadfence();          // drain this thread's stores (per-wave wb)
    __syncthreads();          // all waves' fences complete before t0's add
    if (threadIdx.x == 0)
        __hip_atomic_fetch_add(f, 1u, __ATOMIC_RELEASE,
                               __HIP_MEMORY_SCOPE_AGENT);
}

__device__ __forceinline__ void waitflag(unsigned int* f, unsigned int tgt) {
    if (threadIdx.x == 0) {
        while (__hip_atomic_load(f, __ATOMIC_RELAXED, __HIP_MEMORY_SCOPE_AGENT) < tgt)
            __builtin_amdgcn_s_sleep(16);
        (void)__hip_atomic_load(f, __ATOMIC_ACQUIRE, __HIP_MEMORY_SCOPE_AGENT);
    }
    __syncthreads();   // fan-out: block-uniform call sites only
}

__global__ __launch_bounds__(RB, 2) void fused_k(
    const float* __restrict__ u, const float* __restrict__ x0,
    const float* __restrict__ A, const float* __restrict__ Bu,
    const float* __restrict__ Cy, const float* __restrict__ Dyu,
    const float* __restrict__ um, const float* __restrict__ us,
    const float* __restrict__ ym, const float* __restrict__ ys,
    float* __restrict__ Y, float* __restrict__ X,
    float* __restrict__ d32, float* __restrict__ d256,
    float* __restrict__ s256, unsigned int* __restrict__ flags) {
    __shared__ float uL[LF][NUI][RB];   // 64 KB normalized u (this chunk)
    __shared__ float Ms[64];
    __shared__ float A32s[64];
    __shared__ float A256s[64];

    const int c = blockIdx.x;   // 0..511
    const int t = threadIdx.x;
    const int r = t;            // column
    const int m = c >> 3;       // super-chunk
    const int p = c & 7;        // position in super-chunk (block-uniform)
    // one flag per 256-B slot: cnt[m] | dcnt | fs[m]
    unsigned int* cnt  = flags + (size_t)m * FPAD;
    unsigned int* dcnt = flags + (size_t)NC2B * FPAD;
    unsigned int* fs   = flags + (size_t)(NC2B + 1 + m) * FPAD;

    // ---- phase A: normalize u -> LDS, zero-state 32-step response ----
    float a[NXS][NXS];
    #pragma unroll
    for (int i = 0; i < NXS; ++i)
        #pragma unroll
        for (int j = 0; j < NXS; ++j) a[i][j] = A[i * NXS + j];
    float b0[NXS], b1[NXS];
    #pragma unroll
    for (int i = 0; i < NXS; ++i) { b0[i] = Bu[i * NUI]; b1[i] = Bu[i * NUI + 1]; }
    const float um0 = um[0], um1 = um[1];
    const float is0 = 1.0f / us[0], is1 = 1.0f / us[1];
    float tv[NXS];
    #pragma unroll
    for (int i = 0; i < NXS; ++i) tv[i] = 0.f;
    {
        const float* up = u + (size_t)c * LF * NUI * RB + r;
        #pragma unroll 4
        for (int j = 0; j < LF; ++j) {
            const float u0 = (up[0]  - um0) * is0;
            const float u1 = (up[RB] - um1) * is1;
            up += NUI * RB;
            uL[j][0][r] = u0;
            uL[j][1][r] = u1;
            float nt[NXS];
            #pragma unroll
            for (int i = 0; i < NXS; ++i) {
                float acc = fmaf(b0[i], u0, b1[i] * u1);
                #pragma unroll
                for (int k = 0; k < NXS; ++k) acc = fmaf(a[i][k], tv[k], acc);
                nt[i] = acc;
            }
            #pragma unroll
            for (int i = 0; i < NXS; ++i) tv[i] = nt[i];
        }
    }
    if (p != 7) {   // combiner's own slice is never read by others
        float* dp = d32 + (size_t)c * NXS * RB + r;
        #pragma unroll
        for (int i = 0; i < NXS; ++i) dp[i * RB] = tv[i];
        publish(cnt);              // block-granular: 1 atomic per block
    }

    // ---- A powers ladder (overlaps other blocks' phase A) ----
    if (t < 64) Ms[t] = A[t];
    __syncthreads();
    {
        const int pi = t >> 3, pj = t & 7;
        #pragma unroll
        for (int it = 0; it < 8; ++it) {   // A^2 .. A^256
            float acc = 0.f;
            if (t < 64) {
                #pragma unroll
                for (int k = 0; k < 8; ++k) acc += Ms[pi * 8 + k] * Ms[k * 8 + pj];
            }
            __syncthreads();
            if (t < 64) {
                Ms[t] = acc;
                if (it == 4) A32s[t] = acc;   // A^32
            }
            __syncthreads();
        }
        if (t < 64) A256s[t] = Ms[t];          // A^256
        __syncthreads();
    }

    float sb[NXS];   // start state of super-chunk m for this column

    if (p == 7) {
        // ---------------- combiner ----------------
        float xv[NXS];
        #pragma unroll
        for (int i = 0; i < NXS; ++i) xv[i] = x0[i * RB + r];

        waitflag(cnt, CNT_TGT);
        {
            float a32[NXS][NXS];
            #pragma unroll
            for (int i = 0; i < NXS; ++i)
                #pragma unroll
                for (int j = 0; j < NXS; ++j) a32[i][j] = A32s[i * 8 + j];
            float xq[NSUP - 1][NXS];
            #pragma unroll
            for (int q = 0; q < NSUP - 1; ++q) {
                const float* dq = d32 + (size_t)(NSUP * m + q) * NXS * RB + r;
                #pragma unroll
                for (int i = 0; i < NXS; ++i) xq[q][i] = dq[i * RB];
            }
            float s[NXS];
            #pragma unroll
            for (int i = 0; i < NXS; ++i) s[i] = xq[0][i];
            #pragma unroll
            for (int q = 1; q < NSUP - 1; ++q) {
                float nt[NXS];
                #pragma unroll
                for (int i = 0; i < NXS; ++i) {
                    float acc = xq[q][i];
                    #pragma unroll
                    for (int k = 0; k < NXS; ++k) acc = fmaf(a32[i][k], s[k], acc);
                    nt[i] = acc;
                }
                #pragma unroll
                for (int i = 0; i < NXS; ++i) s[i] = nt[i];
            }
            {   // last term = own tv (in registers)
                float nt[NXS];
                #pragma unroll
                for (int i = 0; i < NXS; ++i) {
                    float acc = tv[i];
                    #pragma unroll
                    for (int k = 0; k < NXS; ++k) acc = fmaf(a32[i][k], s[k], acc);
                    nt[i] = acc;
                }
                #pragma unroll
                for (int i = 0; i < NXS; ++i) s[i] = nt[i];
            }
            float* o = d256 + (size_t)m * NXS * RB + r;
            #pragma unroll
            for (int i = 0; i < NXS; ++i) o[i * RB] = s[i];
        }
        publish(dcnt);

        // lookback: sb = Horner_{A256}(d256[0..m-1]) from x0
        #pragma unroll
        for (int i = 0; i < NXS; ++i) sb[i] = xv[i];
        if (m > 0) {
            waitflag(dcnt, DCNT_TGT);
            float a256[NXS][NXS];
            #pragma unroll
            for (int i = 0; i < NXS; ++i)
                #pragma unroll
                for (int j = 0; j < NXS; ++j) a256[i][j] = A256s[i * 8 + j];
            for (int base = 0; base < m; base += 8) {   // <=8 tiles
                float T[8][NXS];
                #pragma unroll
                for (int k = 0; k < 8; ++k) {
                    if (base + k < m) {
                        const float* dq = d256 + (size_t)(base + k) * NXS * RB + r;
                        #pragma unroll
                        for (int i = 0; i < NXS; ++i) T[k][i] = dq[i * RB];
                    }
                }
                #pragma unroll
                for (int k = 0; k < 8; ++k) {
                    if (base + k < m) {
                        float nt[NXS];
                        #pragma unroll
                        for (int i = 0; i < NXS; ++i) {
                            float acc = T[k][i];
                            #pragma unroll
                            for (int kk = 0; kk < NXS; ++kk)
                                acc = fmaf(a256[i][kk], sb[kk], acc);
                            nt[i] = acc;
                        }
                        #pragma unroll
                        for (int i = 0; i < NXS; ++i) sb[i] = nt[i];
                    }
                }
            }
        }
        {
            float* sp = s256 + (size_t)m * NXS * RB + r;
            #pragma unroll
            for (int i = 0; i < NXS; ++i) sp[i * RB] = sb[i];
        }
        publish(fs);
    } else {
        // ---------------- consumer ----------------
        waitflag(fs, FS_TGT);
        const float* sp = s256 + (size_t)m * NXS * RB + r;
        #pragma unroll
        for (int i = 0; i < NXS; ++i) sb[i] = sp[i * RB];
    }

    // ---- advance start by p fine chunks: sb = A32 sb + d32[8m+q] ----
    if (p) {
        float a32[NXS][NXS];
        #pragma unroll
        for (int i = 0; i < NXS; ++i)
            #pragma unroll
            for (int j = 0; j < NXS; ++j) a32[i][j] = A32s[i * 8 + j];
        float P[NSUP - 1][NXS];
        #pragma unroll
        for (int q = 0; q < NSUP - 1; ++q) {
            if (q < p) {
                const float* dq = d32 + (size_t)(NSUP * m + q) * NXS * RB + r;
                #pragma unroll
                for (int i = 0; i < NXS; ++i) P[q][i] = dq[i * RB];
            }
        }
        #pragma unroll
        for (int q = 0; q < NSUP - 1; ++q) {
            if (q < p) {
                float nt[NXS];
                #pragma unroll
                for (int i = 0; i < NXS; ++i) {
                    float acc = P[q][i];
                    #pragma unroll
                    for (int k = 0; k < NXS; ++k) acc = fmaf(a32[i][k], sb[k], acc);
                    nt[i] = acc;
                }
                #pragma unroll
                for (int i = 0; i < NXS; ++i) sb[i] = nt[i];
            }
        }
    }

    // ---- replay 32 steps from LDS u; nt-store X and denormalized Y ----
    float c0[NXS], c1[NXS];
    #pragma unroll
    for (int k = 0; k < NXS; ++k) { c0[k] = Cy[k]; c1[k] = Cy[NXS + k]; }
    const float d00 = Dyu[0], d01 = Dyu[1], d10 = Dyu[2], d11 = Dyu[3];
    const float ym0 = ym[0], ym1 = ym[1], ys0 = ys[0], ys1 = ys[1];
    float* Xp = X + (size_t)c * LF * NXS * RB + r;
    float* Yp = Y + (size_t)c * LF * NYO * RB + r;
    #pragma unroll 4
    for (int j = 0; j < LF; ++j) {
        const float u0 = uL[j][0][r];
        const float u1 = uL[j][1][r];
        #pragma unroll
        for (int i = 0; i < NXS; ++i)
            __builtin_nontemporal_store(sb[i], Xp + i * RB);
        Xp += NXS * RB;
        float y0 = fmaf(d00, u0, d01 * u1);
        float y1 = fmaf(d10, u0, d11 * u1);
        #pragma unroll
        for (int k = 0; k < NXS; ++k) {
            y0 = fmaf(c0[k], sb[k], y0);
            y1 = fmaf(c1[k], sb[k], y1);
        }
        __builtin_nontemporal_store(fmaf(y0, ys0, ym0), Yp);
        __builtin_nontemporal_store(fmaf(y1, ys1, ym1), Yp + RB);
        Yp += NYO * RB;
        float nt[NXS];
        #pragma unroll
        for (int i = 0; i < NXS; ++i) {
            float acc = fmaf(b0[i], u0, b1[i] * u1);
            #pragma unroll
            for (int k = 0; k < NXS; ++k) acc = fmaf(a[i][k], sb[k], acc);
            nt[i] = acc;
        }
        #pragma unroll
        for (int i = 0; i < NXS; ++i) sb[i] = nt[i];
    }
}

extern "C" void kernel_launch(void* const* d_in, const int* in_sizes, int n_in,
                              void* d_out, int out_size, void* d_ws, size_t ws_size,
                              hipStream_t stream) {
    const float* u   = (const float*)d_in[0];
    const float* x0  = (const float*)d_in[1];
    const float* A   = (const float*)d_in[2];
    const float* Bu  = (const float*)d_in[3];
    const float* Cy  = (const float*)d_in[4];
    const float* Dyu = (const float*)d_in[5];
    const float* um  = (const float*)d_in[6];
    const float* us  = (const float*)d_in[7];
    const float* ym  = (const float*)d_in[8];
    const float* ys  = (const float*)d_in[9];

    float* Y = (float*)d_out;                       // (N, NY, R)
    float* X = Y + (size_t)NSTEPS * NYO * RB;       // (N, NX, R)

    float* ws   = (float*)d_ws;
    float* d32  = ws;                               // NC1*NX*R  = 4 MB
    float* d256 = d32 + (size_t)NC1 * NXS * RB;     // NC2B*NX*R = 512 KB
    float* s256 = d256 + (size_t)NC2B * NXS * RB;   // NC2B*NX*R = 512 KB
    unsigned int* flags = (unsigned int*)(s256 + (size_t)NC2B * NXS * RB);

    // flags: (64+1+64) slots x 256 B = 33024 B; zero each run (ws poisoned)
    hipMemsetAsync(flags, 0, (size_t)(2 * NC2B + 1) * FPAD * 4, stream);
    fused_k<<<NC1, RB, 0, stream>>>(u, x0, A, Bu, Cy, Dyu, um, us, ym, ys,
                                    Y, X, d32, d256, s256, flags);
}

// Round 7
// 223.589 us; speedup vs baseline: 1.9354x; 1.8924x over previous
//
#include <hip/hip_runtime.h>

// Linear state-space scan:  x_{k+1} = A x_k + B u_k ; outputs X_k (pre-step
// state) and y_k = C x_k + D u_k (normalized in, denormalized out).
// N=16384 steps, R=256 columns, NX=8, NU=NY=2.
//
// Blocked parallel linear scan, 3 stream-ordered dispatches.
//   Session evidence: cross-block sync INSIDE a kernel is ~100-200us on
//   MI355X regardless of mechanism (cg grid.sync ~110us/sync; flag-based
//   rounds 3-5 all ~190-220us idle, invariant to atomic count / line
//   padding / publish granularity). Dispatch boundaries are the only cheap
//   producer->consumer sync. So: minimize dispatches, never sync in-kernel.
//   phase1_k:   zero-state response d32[c] of 512 chunks x 32 steps
//   combine8_k: d256[m] = Horner_{A32}(d32[8m..8m+7])   (64 blocks)
//   phase3_k:   per-block redundant lookback s256[m] = Horner_{A256}
//               (d256[0..m-1]) from x0 (d256 is 512KB -> L2-resident;
//               replaces the serial 4-block phase2 dispatch + 1 gap),
//               advance p=c&7 fine chunks via d32, replay 32 steps,
//               nt-store X and denormalized Y.
// A-powers computed per-block in LDS (8x8 repeated squaring, ~0.3us).

#define NSTEPS 16384
#define NUI 2
#define RB 256
#define NXS 8
#define NYO 2
#define LF 32
#define NC1 (NSTEPS / LF)   // 512 fine chunks (32 steps each)
#define NSUP 8              // fine chunks per super-chunk
#define NC2B (NC1 / NSUP)   // 64 super-chunks of 256 steps

// ---------------------------------------------------------------- phase1
__global__ __launch_bounds__(RB) void phase1_k(
    const float* __restrict__ u, const float* __restrict__ A,
    const float* __restrict__ Bu, const float* __restrict__ um,
    const float* __restrict__ us, float* __restrict__ d32) {
    const int c = blockIdx.x;
    const int r = threadIdx.x;
    float a[NXS][NXS];
    #pragma unroll
    for (int i = 0; i < NXS; ++i)
        #pragma unroll
        for (int j = 0; j < NXS; ++j) a[i][j] = A[i * NXS + j];
    float b0[NXS], b1[NXS];
    #pragma unroll
    for (int i = 0; i < NXS; ++i) { b0[i] = Bu[i * NUI]; b1[i] = Bu[i * NUI + 1]; }
    const float um0 = um[0], um1 = um[1];
    const float is0 = 1.0f / us[0], is1 = 1.0f / us[1];
    float t[NXS];
    #pragma unroll
    for (int i = 0; i < NXS; ++i) t[i] = 0.f;
    const float* up = u + (size_t)c * LF * NUI * RB + r;
    #pragma unroll 4
    for (int j = 0; j < LF; ++j) {
        const float u0 = (up[0]  - um0) * is0;
        const float u1 = (up[RB] - um1) * is1;
        up += NUI * RB;
        float nt[NXS];
        #pragma unroll
        for (int i = 0; i < NXS; ++i) {
            float acc = fmaf(b0[i], u0, b1[i] * u1);
            #pragma unroll
            for (int k = 0; k < NXS; ++k) acc = fmaf(a[i][k], t[k], acc);
            nt[i] = acc;
        }
        #pragma unroll
        for (int i = 0; i < NXS; ++i) t[i] = nt[i];
    }
    float* dp = d32 + (size_t)c * NXS * RB + r;
    #pragma unroll
    for (int i = 0; i < NXS; ++i) dp[i * RB] = t[i];
}

// ---------------------------------------------------------------- combine8
// d256[m] = A32^7 d32[8m] + ... + d32[8m+7]   (Horner, A32 in-block)
__global__ __launch_bounds__(RB) void combine8_k(
    const float* __restrict__ d32, const float* __restrict__ A,
    float* __restrict__ d256) {
    __shared__ float Ms[64];
    __shared__ float A32s[64];
    const int m = blockIdx.x;
    const int t = threadIdx.x;
    const int r = t;

    // issue all 64 global loads first — latency overlaps the A32 computation
    float xq[NSUP][NXS];
    #pragma unroll
    for (int q = 0; q < NSUP; ++q) {
        const float* dq = d32 + (size_t)(NSUP * m + q) * NXS * RB + r;
        #pragma unroll
        for (int i = 0; i < NXS; ++i) xq[q][i] = dq[i * RB];
    }

    if (t < 64) Ms[t] = A[t];
    __syncthreads();
    {
        const int pi = t >> 3, pj = t & 7;
        for (int it = 0; it < 5; ++it) {   // A^2, A^4, A^8, A^16, A^32
            float acc = 0.f;
            if (t < 64) {
                #pragma unroll
                for (int k = 0; k < 8; ++k) acc += Ms[pi * 8 + k] * Ms[k * 8 + pj];
            }
            __syncthreads();
            if (t < 64) Ms[t] = acc;
            __syncthreads();
        }
        if (t < 64) A32s[t] = Ms[t];
        __syncthreads();
    }

    float a32[NXS][NXS];
    #pragma unroll
    for (int i = 0; i < NXS; ++i)
        #pragma unroll
        for (int j = 0; j < NXS; ++j) a32[i][j] = A32s[i * 8 + j];

    float s[NXS];
    #pragma unroll
    for (int i = 0; i < NXS; ++i) s[i] = xq[0][i];
    #pragma unroll
    for (int q = 1; q < NSUP; ++q) {
        float nt[NXS];
        #pragma unroll
        for (int i = 0; i < NXS; ++i) {
            float acc = xq[q][i];
            #pragma unroll
            for (int k = 0; k < NXS; ++k) acc = fmaf(a32[i][k], s[k], acc);
            nt[i] = acc;
        }
        #pragma unroll
        for (int i = 0; i < NXS; ++i) s[i] = nt[i];
    }
    float* o = d256 + (size_t)m * NXS * RB + r;
    #pragma unroll
    for (int i = 0; i < NXS; ++i) o[i * RB] = s[i];
}

// ---------------------------------------------------------------- phase3
// Per-block lookback (replaces phase2): sb = Horner_{A256}(d256[0..m-1])
// from x0; then advance p fine chunks via d32; replay 32 steps; nt-store.
__global__ __launch_bounds__(RB) void phase3_k(
    const float* __restrict__ u, const float* __restrict__ x0,
    const float* __restrict__ d32, const float* __restrict__ d256,
    const float* __restrict__ A, const float* __restrict__ Bu,
    const float* __restrict__ Cy, const float* __restrict__ Dyu,
    const float* __restrict__ um, const float* __restrict__ us,
    const float* __restrict__ ym, const float* __restrict__ ys,
    float* __restrict__ Y, float* __restrict__ X) {
    __shared__ float Ms[64];
    __shared__ float A32s[64];
    __shared__ float A256s[64];
    const int c = blockIdx.x;   // 0..511
    const int t = threadIdx.x;
    const int r = t;
    const int m = c >> 3;
    const int p = c & 7;        // block-uniform

    // issue x0 load first (latency hides under the power ladder)
    float sb[NXS];
    #pragma unroll
    for (int i = 0; i < NXS; ++i) sb[i] = x0[i * RB + r];

    // A-power ladder: A^2..A^256; stash A^32 and A^256
    if (t < 64) Ms[t] = A[t];
    __syncthreads();
    {
        const int pi = t >> 3, pj = t & 7;
        for (int it = 0; it < 8; ++it) {
            float acc = 0.f;
            if (t < 64) {
                #pragma unroll
                for (int k = 0; k < 8; ++k) acc += Ms[pi * 8 + k] * Ms[k * 8 + pj];
            }
            __syncthreads();
            if (t < 64) {
                Ms[t] = acc;
                if (it == 4) A32s[t] = acc;   // A^32
            }
            __syncthreads();
        }
        if (t < 64) A256s[t] = Ms[t];          // A^256
        __syncthreads();
    }

    // lookback: sb = Horner_{A256}(d256[0..m-1]) from x0 (same op sequence
    // as the verified serial phase2; d256 is 512KB -> L2-resident re-read)
    if (m > 0) {
        float a256[NXS][NXS];
        #pragma unroll
        for (int i = 0; i < NXS; ++i)
            #pragma unroll
            for (int j = 0; j < NXS; ++j) a256[i][j] = A256s[i * 8 + j];
        for (int base = 0; base < m; base += 8) {   // <=8 tiles
            float T[8][NXS];
            #pragma unroll
            for (int k = 0; k < 8; ++k) {
                if (base + k < m) {
                    const float* dq = d256 + (size_t)(base + k) * NXS * RB + r;
                    #pragma unroll
                    for (int i = 0; i < NXS; ++i) T[k][i] = dq[i * RB];
                }
            }
            #pragma unroll
            for (int k = 0; k < 8; ++k) {
                if (base + k < m) {
                    float nt[NXS];
                    #pragma unroll
                    for (int i = 0; i < NXS; ++i) {
                        float acc = T[k][i];
                        #pragma unroll
                        for (int kk = 0; kk < NXS; ++kk)
                            acc = fmaf(a256[i][kk], sb[kk], acc);
                        nt[i] = acc;
                    }
                    #pragma unroll
                    for (int i = 0; i < NXS; ++i) sb[i] = nt[i];
                }
            }
        }
    }

    // advance start by p fine chunks: sb = A32 sb + d32[8m+q]
    if (p) {
        float a32[NXS][NXS];
        #pragma unroll
        for (int i = 0; i < NXS; ++i)
            #pragma unroll
            for (int j = 0; j < NXS; ++j) a32[i][j] = A32s[i * 8 + j];
        float P[NSUP - 1][NXS];
        #pragma unroll
        for (int q = 0; q < NSUP - 1; ++q) {
            if (q < p) {
                const float* dq = d32 + (size_t)(NSUP * m + q) * NXS * RB + r;
                #pragma unroll
                for (int i = 0; i < NXS; ++i) P[q][i] = dq[i * RB];
            }
        }
        #pragma unroll
        for (int q = 0; q < NSUP - 1; ++q) {
            if (q < p) {
                float nt[NXS];
                #pragma unroll
                for (int i = 0; i < NXS; ++i) {
                    float acc = P[q][i];
                    #pragma unroll
                    for (int k = 0; k < NXS; ++k) acc = fmaf(a32[i][k], sb[k], acc);
                    nt[i] = acc;
                }
                #pragma unroll
                for (int i = 0; i < NXS; ++i) sb[i] = nt[i];
            }
        }
    }

    // replay 32 steps; nt-store X and denormalized Y
    float a[NXS][NXS];
    #pragma unroll
    for (int i = 0; i < NXS; ++i)
        #pragma unroll
        for (int j = 0; j < NXS; ++j) a[i][j] = A[i * NXS + j];
    float b0[NXS], b1[NXS], c0[NXS], c1[NXS];
    #pragma unroll
    for (int i = 0; i < NXS; ++i) { b0[i] = Bu[i * NUI]; b1[i] = Bu[i * NUI + 1]; }
    #pragma unroll
    for (int k = 0; k < NXS; ++k) { c0[k] = Cy[k]; c1[k] = Cy[NXS + k]; }
    const float d00 = Dyu[0], d01 = Dyu[1], d10 = Dyu[2], d11 = Dyu[3];
    const float um0 = um[0], um1 = um[1];
    const float is0 = 1.0f / us[0], is1 = 1.0f / us[1];
    const float ym0 = ym[0], ym1 = ym[1], ys0 = ys[0], ys1 = ys[1];

    const float* up = u + (size_t)c * LF * NUI * RB + r;
    float* Xp = X + (size_t)c * LF * NXS * RB + r;
    float* Yp = Y + (size_t)c * LF * NYO * RB + r;
    #pragma unroll 4
    for (int j = 0; j < LF; ++j) {
        const float u0 = (up[0]  - um0) * is0;
        const float u1 = (up[RB] - um1) * is1;
        up += NUI * RB;
        #pragma unroll
        for (int i = 0; i < NXS; ++i)
            __builtin_nontemporal_store(sb[i], Xp + i * RB);
        Xp += NXS * RB;
        float y0 = fmaf(d00, u0, d01 * u1);
        float y1 = fmaf(d10, u0, d11 * u1);
        #pragma unroll
        for (int k = 0; k < NXS; ++k) {
            y0 = fmaf(c0[k], sb[k], y0);
            y1 = fmaf(c1[k], sb[k], y1);
        }
        __builtin_nontemporal_store(fmaf(y0, ys0, ym0), Yp);
        __builtin_nontemporal_store(fmaf(y1, ys1, ym1), Yp + RB);
        Yp += NYO * RB;
        float nt[NXS];
        #pragma unroll
        for (int i = 0; i < NXS; ++i) {
            float acc = fmaf(b0[i], u0, b1[i] * u1);
            #pragma unroll
            for (int k = 0; k < NXS; ++k) acc = fmaf(a[i][k], sb[k], acc);
            nt[i] = acc;
        }
        #pragma unroll
        for (int i = 0; i < NXS; ++i) sb[i] = nt[i];
    }
}

extern "C" void kernel_launch(void* const* d_in, const int* in_sizes, int n_in,
                              void* d_out, int out_size, void* d_ws, size_t ws_size,
                              hipStream_t stream) {
    const float* u   = (const float*)d_in[0];
    const float* x0  = (const float*)d_in[1];
    const float* A   = (const float*)d_in[2];
    const float* Bu  = (const float*)d_in[3];
    const float* Cy  = (const float*)d_in[4];
    const float* Dyu = (const float*)d_in[5];
    const float* um  = (const float*)d_in[6];
    const float* us  = (const float*)d_in[7];
    const float* ym  = (const float*)d_in[8];
    const float* ys  = (const float*)d_in[9];

    float* Y = (float*)d_out;                       // (N, NY, R)
    float* X = Y + (size_t)NSTEPS * NYO * RB;       // (N, NX, R)

    float* ws   = (float*)d_ws;
    float* d32  = ws;                               // NC1*NX*R  = 4 MB
    float* d256 = d32 + (size_t)NC1 * NXS * RB;     // NC2B*NX*R = 512 KB

    phase1_k<<<NC1, RB, 0, stream>>>(u, A, Bu, um, us, d32);
    combine8_k<<<NC2B, RB, 0, stream>>>(d32, A, d256);
    phase3_k<<<NC1, RB, 0, stream>>>(u, x0, d32, d256, A, Bu, Cy, Dyu,
                                     um, us, ym, ys, Y, X);
}